// Round 3
// baseline (430.075 us; speedup 1.0000x reference)
//
#include <hip/hip_runtime.h>

#define Bn 256
#define Tn 2048
#define Pn 64

typedef float f32x2 __attribute__((ext_vector_type(2)));

// ---------------------------------------------------------------------------
// Linear-chain CRF mean NLL.  nll = mean_b( logZ_b - emit_b - trans_b )
// k1 crf_chain: 512 waves. Block 2b = fwd alpha chain (1024 steps), 2b+1 =
//   bwd gamma chain (1022 steps + bare matvec). State p[j]=exp(alpha[j]-C)
//   lives one-value-per-lane; per-step broadcast via 64 v_readlane into SGPR
//   pairs feeding v_pk_fma_f32 (NO LDS on the critical path). Label scores
//   (emit via readlane of the already-loaded u_t register, trans via scalar
//   A-gathers prefetched 1 iter ahead) are folded in nearly for free.
// k2 crf_logz: 256 waves, midpoint dot -> logZ, atomicAdd mean.
// ---------------------------------------------------------------------------

__device__ __forceinline__ void pk_fma_s(f32x2& acc, unsigned long long s, f32x2 b) {
    asm("v_pk_fma_f32 %0, %1, %2, %0" : "+v"(acc) : "s"(s), "v"(b));
}
__device__ __forceinline__ f32x2 pk_mul_s(unsigned long long s, f32x2 b) {
    f32x2 d;
    asm("v_pk_mul_f32 %0, %1, %2" : "=v"(d) : "s"(s), "v"(b));
    return d;
}
__device__ __forceinline__ f32x2 pk_add(f32x2 a, f32x2 b) {
    f32x2 d;
    asm("v_pk_add_f32 %0, %1, %2" : "=v"(d) : "v"(a), "v"(b));
    return d;
}

__device__ __forceinline__ float readlane_f(float v, int lane) {
    return __int_as_float(__builtin_amdgcn_readlane(__float_as_int(v), lane));
}
__device__ __forceinline__ float lane0_bcast(float v) {
    return __int_as_float(__builtin_amdgcn_readfirstlane(__float_as_int(v)));
}

// new_p_lane = sum_i p_i * eA2[i/2][i&1]  — p broadcast via readlane pairs.
__device__ __forceinline__ float matvec_rl(float p, const f32x2* eA2) {
    const int pi = __float_as_int(p);
    f32x2 acc[8];
#pragma unroll
    for (int m = 0; m < 32; ++m) {
        unsigned int lo = (unsigned int)__builtin_amdgcn_readlane(pi, 2 * m);
        unsigned int hi = (unsigned int)__builtin_amdgcn_readlane(pi, 2 * m + 1);
        unsigned long long sv = ((unsigned long long)hi << 32) | lo;
        if (m < 8) acc[m] = pk_mul_s(sv, eA2[m]);
        else       pk_fma_s(acc[m & 7], sv, eA2[m]);
    }
    f32x2 r0 = pk_add(pk_add(acc[0], acc[1]), pk_add(acc[2], acc[3]));
    f32x2 r1 = pk_add(pk_add(acc[4], acc[5]), pk_add(acc[6], acc[7]));
    r0 = pk_add(r0, r1);
    return r0.x + r0.y;
}

__global__ __launch_bounds__(64) void crf_chain(
        const float* __restrict__ unary, const int* __restrict__ labels,
        const float* __restrict__ A, float* __restrict__ wsState,
        float* __restrict__ wsC, float* __restrict__ out) {
    const int bid = blockIdx.x;
    const int b   = bid >> 1;
    const int dir = bid & 1;   // 0 = forward, 1 = backward
    const int j   = threadIdx.x;

    // lane j: fwd holds column j of exp(A); bwd holds row j (packed pairs).
    f32x2 eA2[32];
#pragma unroll
    for (int m = 0; m < 32; ++m) {
        int i0 = 2 * m, i1 = 2 * m + 1;
        float a0 = (dir == 0) ? A[i0 * Pn + j] : A[j * Pn + i0];
        float a1 = (dir == 0) ? A[i1 * Pn + j] : A[j * Pn + i1];
        f32x2 t = {__expf(a0), __expf(a1)};
        eA2[m] = t;
    }

    const float* ub = unary + (size_t)b * Tn * Pn;
    const int*   lb = labels + b * Tn;

    const int t0 = (dir == 0) ? 0 : (Tn - 1);
    const int sd = (dir == 0) ? 1 : -1;

    // init state + init emission score
    float p, C, sc;
    int lab0;
    {
        float u0 = ub[(size_t)t0 * Pn + j];
        lab0 = lb[t0];
        sc = readlane_f(u0, lab0);              // emit at t0
        float m0 = lane0_bcast(u0);
        p = __expf(u0 - m0);
        C = m0;
    }

    const ptrdiff_t ustep = (ptrdiff_t)sd * Pn;
    const float* up = ub + j + (ptrdiff_t)(t0 + sd) * Pn;
    const int*   lp = lb + t0 + sd;

    // prefetch queues: unary (per-lane, VMEM), labels + A-values (uniform, SMEM)
    float uq[8];
    int   labs[8];
    float Aq[8];
#pragma unroll
    for (int k = 0; k < 8; ++k) { uq[k] = up[ustep * k]; labs[k] = lp[sd * k]; }
    {
        int o = lab0;
#pragma unroll
        for (int k = 0; k < 8; ++k) {
            int c = labs[k];
            Aq[k] = (dir == 0) ? A[o * Pn + c] : A[c * Pn + o];
            o = c;
        }
    }

    const int nquad = (dir == 0) ? 128 : 127;   // x8 steps
    int lprev = lab0;

    for (int q = 0; q < nquad; ++q) {
#pragma unroll
        for (int k = 0; k < 8; ++k) {
            float uval = uq[k];
            int   lc   = labs[k];
            float eu = __expf(uval);
            sc += readlane_f(uval, lc);         // emission u_t[lab_t]
            sc += Aq[k];                        // transition
            uq[k]   = up[ustep * (8 + k)];      // prefetch u, 8 steps ahead
            labs[k] = lp[sd * (8 + k)];         // prefetch label
            float s = matvec_rl(p, eA2);
            p = s * eu;
            if ((k & 3) == 3) {                 // renorm every 4 steps
                float p0 = lane0_bcast(p);
                p *= __builtin_amdgcn_rcpf(p0);
                C += __logf(p0);
            }
            lprev = lc;
        }
        {   // refill A-queue for next iter's pairs (consumed >=1 full iter later)
            int o = lprev;
#pragma unroll
            for (int k = 0; k < 8; ++k) {
                int c = labs[k];
                Aq[k] = (dir == 0) ? A[o * Pn + c] : A[c * Pn + o];
                o = c;
            }
        }
        up += ustep * 8;
        lp += sd * 8;
    }

    if (dir == 1) {
        // tail: 6 steps (t = 1030..1025 live in uq/labs/Aq slots 0..5)
#pragma unroll
        for (int k = 0; k < 6; ++k) {
            float uval = uq[k];
            int   lc   = labs[k];
            float eu = __expf(uval);
            sc += readlane_f(uval, lc);
            sc += Aq[k];
            float s = matvec_rl(p, eA2);
            p = s * eu;
            if (k == 3) {
                float p0 = lane0_bcast(p);
                p *= __builtin_amdgcn_rcpf(p0);
                C += __logf(p0);
            }
        }
        // remaining transition pair (1024,1025): labs[6]=lab@1024, labs[5]=lab@1025
        sc += A[labs[6] * Pn + labs[5]];
        // bare matvec (transition only) -> beta-like state at the midpoint
        p = matvec_rl(p, eA2);
    }

    wsState[(size_t)bid * Pn + j] = p;
    if (j == 0) {
        wsC[bid] = C;
        atomicAdd(out, -sc * (1.0f / Bn));      // -(emit+trans partial)/B
    }
}

__global__ __launch_bounds__(64) void crf_logz(
        const float* __restrict__ wsState, const float* __restrict__ wsC,
        float* __restrict__ out) {
    const int b = blockIdx.x;
    const int j = threadIdx.x;
    float d = wsState[(size_t)(2 * b) * Pn + j] *
              wsState[(size_t)(2 * b + 1) * Pn + j];
#pragma unroll
    for (int off = 32; off > 0; off >>= 1) d += __shfl_xor(d, off, 64);
    if (j == 0) {
        float logZ = wsC[2 * b] + wsC[2 * b + 1] + __logf(d);
        atomicAdd(out, logZ * (1.0f / Bn));
    }
}

extern "C" void kernel_launch(void* const* d_in, const int* in_sizes, int n_in,
                              void* d_out, int out_size, void* d_ws, size_t ws_size,
                              hipStream_t stream) {
    const float* unary  = (const float*)d_in[0];
    const int*   labels = (const int*)d_in[1];
    const float* A      = (const float*)d_in[2];

    float* wsState = (float*)d_ws;              // 512 * 64 floats
    float* wsC     = wsState + 512 * Pn;        // 512 floats

    hipMemsetAsync(d_out, 0, sizeof(float), stream);
    crf_chain<<<512, 64, 0, stream>>>(unary, labels, A, wsState, wsC,
                                      (float*)d_out);
    crf_logz<<<Bn, 64, 0, stream>>>(wsState, wsC, (float*)d_out);
}